// Round 1
// baseline (660.527 us; speedup 1.0000x reference)
//
#include <hip/hip_runtime.h>

typedef __attribute__((ext_vector_type(4))) int int4v;
typedef __attribute__((ext_vector_type(4))) float float4v;

#define QMAX 127.0f

// ---------------- Per-row absmax int8 quantization ----------------
// One block per row, 256 threads. K must be 4096 (16 elems/thread).
// Per-element IEEE fp32 division replaced by one double-precision
// reciprocal per row + f64 multiply per element: (float)((double)v * inv)
// differs from correctly-rounded v/s only within ~2^-52 rel of a float
// rounding boundary (expected ~0.2 elements across the whole problem,
// and rintf only cares at half-integer boundaries on top of that).
__global__ __launch_bounds__(256) void quant_rows_kernel(
    const float* __restrict__ a, signed char* __restrict__ q,
    float* __restrict__ scale, int K)
{
    const int row = blockIdx.x;
    const int t = threadIdx.x;
    const float4v* ap = (const float4v*)(a + (size_t)row * K);

    float4v v[4];
#pragma unroll
    for (int i = 0; i < 4; ++i) v[i] = ap[t + 256 * i];

    float m = 0.f;
#pragma unroll
    for (int i = 0; i < 4; ++i) {
        m = fmaxf(m, fabsf(v[i].x));
        m = fmaxf(m, fabsf(v[i].y));
        m = fmaxf(m, fabsf(v[i].z));
        m = fmaxf(m, fabsf(v[i].w));
    }
#pragma unroll
    for (int off = 32; off > 0; off >>= 1)
        m = fmaxf(m, __shfl_down(m, off, 64));
    __shared__ float wmax[4];
    if ((t & 63) == 0) wmax[t >> 6] = m;
    __syncthreads();
    const float am = fmaxf(fmaxf(wmax[0], wmax[1]), fmaxf(wmax[2], wmax[3]));
    const float s = fmaxf(am, 1e-8f) / QMAX;
    if (t == 0) scale[row] = s;

    const double inv = 1.0 / (double)s;   // one f64 division per thread

    int* qrow = (int*)(q + (size_t)row * K);
#pragma unroll
    for (int i = 0; i < 4; ++i) {
        float r0f = (float)((double)v[i].x * inv);
        float r1f = (float)((double)v[i].y * inv);
        float r2f = (float)((double)v[i].z * inv);
        float r3f = (float)((double)v[i].w * inv);
        int b0 = (int)fminf(fmaxf(rintf(r0f), -QMAX), QMAX);
        int b1 = (int)fminf(fmaxf(rintf(r1f), -QMAX), QMAX);
        int b2 = (int)fminf(fmaxf(rintf(r2f), -QMAX), QMAX);
        int b3 = (int)fminf(fmaxf(rintf(r3f), -QMAX), QMAX);
        qrow[t + 256 * i] =
            (b0 & 0xff) | ((b1 & 0xff) << 8) | ((b2 & 0xff) << 16) | ((b3 & 0xff) << 24);
    }
}

// ---------------- int8 GEMM: 128x256 block, wave tile 64x128 ----------------
// C[t,o] = sum_k qx[t,k]*qw[o,k]. BK=64 bytes, 256 threads = 4 waves (2x2),
// wave tile 64x128 = 4x8 grid of mfma_i32_16x16x64_i8.
// LDS xor-swizzle: chunk (row r, col c) stored at column (c + (r>>1)) & 3,
// implemented by permuting the global source address (global_load_lds pins
// LDS dest = uniform base + lane*16). Readers use (q + (l16>>1)) & 3.
//
// Pipeline (T3/T4-lite): double-buffered LDS, stage tile k+1 BEFORE compute
// of tile k, raw s_barrier (no vmcnt(0) drain), counted s_waitcnt vmcnt(6)
// so the next tile's 6 global_load_lds stay in flight across the whole
// compute phase. 2-tile unrolled loop keeps buffer indices compile-time
// constant (no scratch). asm "" memory fences pin compiler ordering around
// each raw barrier.
__global__ __launch_bounds__(256, 3) void gemm_i8_kernel(
    const signed char* __restrict__ qx,   // [M,K]
    const signed char* __restrict__ qw,   // [N,K]
    const float* __restrict__ sx,         // [M]
    const float* __restrict__ sw,         // [N]
    const float* __restrict__ bias,       // [N]
    float* __restrict__ out,              // [M,N]
    int M, int N, int K)
{
    __shared__ signed char smA[2][128 * 64];   // 2 x 8 KB
    __shared__ signed char smB[2][256 * 64];   // 2 x 16 KB

    const int t = threadIdx.x;
    const int lane = t & 63;
    const int wave = t >> 6;

    // XCD-aware bijective swizzle of the linear block id.
    // nwg = 16*64 = 1024, divisible by 8 -> simple remap is bijective.
    // Each XCD then owns a contiguous range = 8 bm-panels (4 MB of qx),
    // which fits its private 4 MB L2.
    const int nx = gridDim.x;
    const int nwg = nx * gridDim.y;
    const int bid = blockIdx.y * nx + blockIdx.x;
    const int cpx = nwg >> 3;
    const int swz = (bid & 7) * cpx + (bid >> 3);
    const int bm = swz / nx;
    const int bn = swz % nx;

    const int wm = (wave >> 1) * 64;   // wave row offset in 128
    const int wn = (wave & 1) * 128;   // wave col offset in 256

    int4v acc[4][8];
#pragma unroll
    for (int i = 0; i < 4; ++i)
#pragma unroll
        for (int j = 0; j < 8; ++j)
            acc[i][j] = (int4v)0;

    // Staging map: chunk ch = t + 256*p -> row ch>>2, swizzled col pos ch&3.
    const int r0 = t >> 2;
    const int c_src = ((t & 3) - ((t >> 3) & 3) + 4) & 3;
    const signed char* gA0 = qx + (size_t)(bm * 128 + r0) * K + c_src * 16;
    const signed char* gA1 = gA0 + (size_t)64 * K;
    const signed char* gB0 = qw + (size_t)(bn * 256 + r0) * K + c_src * 16;
    const signed char* gB1 = gB0 + (size_t)64 * K;
    const signed char* gB2 = gB1 + (size_t)64 * K;
    const signed char* gB3 = gB2 + (size_t)64 * K;

    // Wave-uniform LDS bases, per buffer (compile-time buffer index only).
    signed char* const lA_0 = smA[0] + wave * 1024;
    signed char* const lA_1 = smA[1] + wave * 1024;
    signed char* const lB_0 = smB[0] + wave * 1024;
    signed char* const lB_1 = smB[1] + wave * 1024;

#define STAGE(b) do {                                                                  \
        __builtin_amdgcn_global_load_lds((const void*)gA0, (void*)(lA_##b),         16, 0, 0); \
        __builtin_amdgcn_global_load_lds((const void*)gA1, (void*)(lA_##b + 4096),  16, 0, 0); \
        __builtin_amdgcn_global_load_lds((const void*)gB0, (void*)(lB_##b),         16, 0, 0); \
        __builtin_amdgcn_global_load_lds((const void*)gB1, (void*)(lB_##b + 4096),  16, 0, 0); \
        __builtin_amdgcn_global_load_lds((const void*)gB2, (void*)(lB_##b + 8192),  16, 0, 0); \
        __builtin_amdgcn_global_load_lds((const void*)gB3, (void*)(lB_##b + 12288), 16, 0, 0); \
        gA0 += 64; gA1 += 64; gB0 += 64; gB1 += 64; gB2 += 64; gB3 += 64;              \
    } while (0)

    // Fragment read offsets (A: row wm+mi*16+l16, k-quad q=lane>>4)
    const int l16 = lane & 15;
    const int kq = lane >> 4;
    const int cr = (kq + ((l16 >> 1) & 3)) & 3;
    const int offA = (wm + l16) * 64 + cr * 16;
    const int offB = (wn + l16) * 64 + cr * 16;

#define COMPUTE(b) do {                                                     \
        int4v aF[4], bF[8];                                                 \
        _Pragma("unroll")                                                   \
        for (int mi = 0; mi < 4; ++mi)                                      \
            aF[mi] = *(const int4v*)(&smA[b][0] + offA + mi * 1024);        \
        _Pragma("unroll")                                                   \
        for (int ni = 0; ni < 8; ++ni)                                      \
            bF[ni] = *(const int4v*)(&smB[b][0] + offB + ni * 1024);        \
        _Pragma("unroll")                                                   \
        for (int mi = 0; mi < 4; ++mi)                                      \
            _Pragma("unroll")                                               \
            for (int ni = 0; ni < 8; ++ni)                                  \
                acc[mi][ni] = __builtin_amdgcn_mfma_i32_16x16x64_i8(        \
                    aF[mi], bF[ni], acc[mi][ni], 0, 0, 0);                  \
    } while (0)

#define FENCE() asm volatile("" ::: "memory")

    const int KITER = K >> 6;   // 64, even

    STAGE(0);                   // tile 0 in flight
    for (int kk = 0; kk < KITER; kk += 2) {
        // ---- tile kk from buf 0; stage tile kk+1 into buf 1 ----
        STAGE(1);
        asm volatile("s_waitcnt vmcnt(6)" ::: "memory");   // tile kk's 6 loads done
        __builtin_amdgcn_s_barrier();
        FENCE();
        COMPUTE(0);
        FENCE();
        __builtin_amdgcn_s_barrier();                      // all reads of buf0 done
        FENCE();
        // ---- tile kk+1 from buf 1; stage tile kk+2 into buf 0 ----
        if (kk + 2 < KITER) {
            STAGE(0);
            asm volatile("s_waitcnt vmcnt(6)" ::: "memory");
        } else {
            asm volatile("s_waitcnt vmcnt(0)" ::: "memory");
        }
        __builtin_amdgcn_s_barrier();
        FENCE();
        COMPUTE(1);
        FENCE();
        __builtin_amdgcn_s_barrier();                      // all reads of buf1 done
        FENCE();
    }
#undef STAGE
#undef COMPUTE
#undef FENCE

    // Epilogue: C/D layout col=lane&15, row=(lane>>4)*4+reg
    const int col0 = lane & 15;
    const int row0 = (lane >> 4) * 4;
#pragma unroll
    for (int mi = 0; mi < 4; ++mi) {
#pragma unroll
        for (int r = 0; r < 4; ++r) {
            const int gm = bm * 128 + wm + mi * 16 + row0 + r;
            const float sxr = sx[gm];
            float* orow = out + (size_t)gm * N + bn * 256 + wn;
#pragma unroll
            for (int ni = 0; ni < 8; ++ni) {
                const int gn_local = ni * 16 + col0;
                const int gn = bn * 256 + wn + gn_local;
                orow[gn_local] = (float)acc[mi][ni][r] * (sxr * sw[gn]) + bias[gn];
            }
        }
    }
    (void)M;
}

extern "C" void kernel_launch(void* const* d_in, const int* in_sizes, int n_in,
                              void* d_out, int out_size, void* d_ws, size_t ws_size,
                              hipStream_t stream) {
    const float* x    = (const float*)d_in[0];
    const float* W    = (const float*)d_in[1];
    const float* bias = (const float*)d_in[2];
    float* out = (float*)d_out;

    const int dout = in_sizes[2];               // 4096
    const int din  = in_sizes[1] / dout;        // 4096
    const int T    = in_sizes[0] / din;         // 8192

    signed char* qx = (signed char*)d_ws;
    signed char* qw = qx + (size_t)T * din;
    float* sx = (float*)(qw + (size_t)dout * din);
    float* sw = sx + T;

    quant_rows_kernel<<<T,    256, 0, stream>>>(x, qx, sx, din);
    quant_rows_kernel<<<dout, 256, 0, stream>>>(W, qw, sw, din);

    dim3 grid(dout / 256, T / 128);
    gemm_i8_kernel<<<grid, 256, 0, stream>>>(qx, qw, sx, sw, bias, out, T, dout, din);

    (void)n_in; (void)out_size; (void)ws_size;
}

// Round 2
// 403.275 us; speedup vs baseline: 1.6379x; 1.6379x over previous
//
#include <hip/hip_runtime.h>

typedef __attribute__((ext_vector_type(4))) int int4v;
typedef __attribute__((ext_vector_type(4))) float float4v;

#define QMAX 127.0f

// ---------------- Per-row absmax int8 quantization (fused x + W) ----------------
// One block per row, 256 threads. K must be 4096 (16 elems/thread).
// Blocks [0,T) handle x rows; blocks [T, T+dout) handle W rows (block-uniform
// select, no divergence). Per-element division replaced by one f64 reciprocal
// per row + f64 multiply per element: (float)((double)v * inv) differs from
// correctly-rounded v/s only within ~2^-52 rel of a float rounding boundary
// (expected ~0.2 elements over the whole problem; verified absmax unchanged).
__global__ __launch_bounds__(256) void quant_rows_fused(
    const float* __restrict__ x, const float* __restrict__ w,
    signed char* __restrict__ qxp, signed char* __restrict__ qwp,
    float* __restrict__ sxp, float* __restrict__ swp,
    int T, int K)
{
    const int blk = blockIdx.x;
    const float* a;
    signed char* q;
    float* scale;
    int row;
    if (blk < T) { a = x; q = qxp; scale = sxp; row = blk; }
    else         { a = w; q = qwp; scale = swp; row = blk - T; }

    const int t = threadIdx.x;
    const float4v* ap = (const float4v*)(a + (size_t)row * K);

    float4v v[4];
#pragma unroll
    for (int i = 0; i < 4; ++i) v[i] = ap[t + 256 * i];

    float m = 0.f;
#pragma unroll
    for (int i = 0; i < 4; ++i) {
        m = fmaxf(m, fabsf(v[i].x));
        m = fmaxf(m, fabsf(v[i].y));
        m = fmaxf(m, fabsf(v[i].z));
        m = fmaxf(m, fabsf(v[i].w));
    }
#pragma unroll
    for (int off = 32; off > 0; off >>= 1)
        m = fmaxf(m, __shfl_down(m, off, 64));
    __shared__ float wmax[4];
    if ((t & 63) == 0) wmax[t >> 6] = m;
    __syncthreads();
    const float am = fmaxf(fmaxf(wmax[0], wmax[1]), fmaxf(wmax[2], wmax[3]));
    const float s = fmaxf(am, 1e-8f) / QMAX;
    if (t == 0) scale[row] = s;

    const double inv = 1.0 / (double)s;   // one f64 division per thread

    int* qrow = (int*)(q + (size_t)row * K);
#pragma unroll
    for (int i = 0; i < 4; ++i) {
        float r0f = (float)((double)v[i].x * inv);
        float r1f = (float)((double)v[i].y * inv);
        float r2f = (float)((double)v[i].z * inv);
        float r3f = (float)((double)v[i].w * inv);
        int b0 = (int)fminf(fmaxf(rintf(r0f), -QMAX), QMAX);
        int b1 = (int)fminf(fmaxf(rintf(r1f), -QMAX), QMAX);
        int b2 = (int)fminf(fmaxf(rintf(r2f), -QMAX), QMAX);
        int b3 = (int)fminf(fmaxf(rintf(r3f), -QMAX), QMAX);
        qrow[t + 256 * i] =
            (b0 & 0xff) | ((b1 & 0xff) << 8) | ((b2 & 0xff) << 16) | ((b3 & 0xff) << 24);
    }
}

// ---------------- int8 GEMM: 128x256 block, wave tile 64x128 ----------------
// C[t,o] = sum_k qx[t,k]*qw[o,k]. BK=64 bytes, 256 threads = 4 waves (2x2),
// wave tile 64x128 = 4x8 grid of mfma_i32_16x16x64_i8.
// LDS xor-swizzle: chunk (row r, col c) stored at column (c + (r>>1)) & 3,
// implemented by permuting the global source address (global_load_lds pins
// LDS dest = uniform base + lane*16). Readers use (q + (l16>>1)) & 3.
//
// Pipeline (T3/T4-lite): double-buffered LDS, stage tile k+1 BEFORE compute
// of tile k, raw s_barrier (no vmcnt(0) drain), counted s_waitcnt vmcnt(6)
// so the next tile's 6 global_load_lds stay in flight across the whole
// compute phase. 2-tile unrolled loop keeps buffer indices compile-time
// constant (no scratch).
//
// NOTE: __launch_bounds__(256, 2). Round-1 evidence: (256,3) made the
// allocator cap arch VGPRs at 84 and spill pipeline live ranges to scratch
// (WRITE_SIZE 131 -> 819 MB, dur 169 -> 406 us). (256,2) gave VGPR=100,
// zero scratch, in the round-0 kernel with identical register structure.
__global__ __launch_bounds__(256, 2) void gemm_i8_kernel(
    const signed char* __restrict__ qx,   // [M,K]
    const signed char* __restrict__ qw,   // [N,K]
    const float* __restrict__ sx,         // [M]
    const float* __restrict__ sw,         // [N]
    const float* __restrict__ bias,       // [N]
    float* __restrict__ out,              // [M,N]
    int M, int N, int K)
{
    __shared__ signed char smA[2][128 * 64];   // 2 x 8 KB
    __shared__ signed char smB[2][256 * 64];   // 2 x 16 KB

    const int t = threadIdx.x;
    const int lane = t & 63;
    const int wave = t >> 6;

    // XCD-aware bijective swizzle of the linear block id (nwg = 1024, /8 ok).
    const int nx = gridDim.x;
    const int nwg = nx * gridDim.y;
    const int bid = blockIdx.y * nx + blockIdx.x;
    const int cpx = nwg >> 3;
    const int swz = (bid & 7) * cpx + (bid >> 3);
    const int bm = swz / nx;
    const int bn = swz % nx;

    const int wm = (wave >> 1) * 64;   // wave row offset in 128
    const int wn = (wave & 1) * 128;   // wave col offset in 256

    int4v acc[4][8];
#pragma unroll
    for (int i = 0; i < 4; ++i)
#pragma unroll
        for (int j = 0; j < 8; ++j)
            acc[i][j] = (int4v)0;

    // Staging map: chunk ch = t + 256*p -> row ch>>2, swizzled col pos ch&3.
    const int r0 = t >> 2;
    const int c_src = ((t & 3) - ((t >> 3) & 3) + 4) & 3;
    const signed char* gA0 = qx + (size_t)(bm * 128 + r0) * K + c_src * 16;
    const signed char* gA1 = gA0 + (size_t)64 * K;
    const signed char* gB0 = qw + (size_t)(bn * 256 + r0) * K + c_src * 16;
    const signed char* gB1 = gB0 + (size_t)64 * K;
    const signed char* gB2 = gB1 + (size_t)64 * K;
    const signed char* gB3 = gB2 + (size_t)64 * K;

    // Wave-uniform LDS bases, per buffer (compile-time buffer index only).
    signed char* const lA_0 = smA[0] + wave * 1024;
    signed char* const lA_1 = smA[1] + wave * 1024;
    signed char* const lB_0 = smB[0] + wave * 1024;
    signed char* const lB_1 = smB[1] + wave * 1024;

#define STAGE(b) do {                                                                  \
        __builtin_amdgcn_global_load_lds((const void*)gA0, (void*)(lA_##b),         16, 0, 0); \
        __builtin_amdgcn_global_load_lds((const void*)gA1, (void*)(lA_##b + 4096),  16, 0, 0); \
        __builtin_amdgcn_global_load_lds((const void*)gB0, (void*)(lB_##b),         16, 0, 0); \
        __builtin_amdgcn_global_load_lds((const void*)gB1, (void*)(lB_##b + 4096),  16, 0, 0); \
        __builtin_amdgcn_global_load_lds((const void*)gB2, (void*)(lB_##b + 8192),  16, 0, 0); \
        __builtin_amdgcn_global_load_lds((const void*)gB3, (void*)(lB_##b + 12288), 16, 0, 0); \
        gA0 += 64; gA1 += 64; gB0 += 64; gB1 += 64; gB2 += 64; gB3 += 64;              \
    } while (0)

    // Fragment read offsets (A: row wm+mi*16+l16, k-quad q=lane>>4)
    const int l16 = lane & 15;
    const int kq = lane >> 4;
    const int cr = (kq + ((l16 >> 1) & 3)) & 3;
    const int offA = (wm + l16) * 64 + cr * 16;
    const int offB = (wn + l16) * 64 + cr * 16;

#define COMPUTE(b) do {                                                     \
        int4v aF[4], bF[8];                                                 \
        _Pragma("unroll")                                                   \
        for (int mi = 0; mi < 4; ++mi)                                      \
            aF[mi] = *(const int4v*)(&smA[b][0] + offA + mi * 1024);        \
        _Pragma("unroll")                                                   \
        for (int ni = 0; ni < 8; ++ni)                                      \
            bF[ni] = *(const int4v*)(&smB[b][0] + offB + ni * 1024);        \
        _Pragma("unroll")                                                   \
        for (int mi = 0; mi < 4; ++mi)                                      \
            _Pragma("unroll")                                               \
            for (int ni = 0; ni < 8; ++ni)                                  \
                acc[mi][ni] = __builtin_amdgcn_mfma_i32_16x16x64_i8(        \
                    aF[mi], bF[ni], acc[mi][ni], 0, 0, 0);                  \
    } while (0)

#define FENCE() asm volatile("" ::: "memory")

    const int KITER = K >> 6;   // 64, even

    STAGE(0);                   // tile 0 in flight
    for (int kk = 0; kk < KITER; kk += 2) {
        // ---- tile kk from buf 0; stage tile kk+1 into buf 1 ----
        STAGE(1);
        asm volatile("s_waitcnt vmcnt(6)" ::: "memory");   // own tile-kk loads done
        __builtin_amdgcn_s_barrier();                      // -> buf0 complete (all waves)
        FENCE();
        COMPUTE(0);
        FENCE();
        __builtin_amdgcn_s_barrier();                      // all reads of buf0 done
        FENCE();
        // ---- tile kk+1 from buf 1; stage tile kk+2 into buf 0 ----
        if (kk + 2 < KITER) {
            STAGE(0);
            asm volatile("s_waitcnt vmcnt(6)" ::: "memory");
        } else {
            asm volatile("s_waitcnt vmcnt(0)" ::: "memory");
        }
        __builtin_amdgcn_s_barrier();
        FENCE();
        COMPUTE(1);
        FENCE();
        __builtin_amdgcn_s_barrier();                      // all reads of buf1 done
        FENCE();
    }
#undef STAGE
#undef COMPUTE
#undef FENCE

    // Epilogue: C/D layout col=lane&15, row=(lane>>4)*4+reg
    const int col0 = lane & 15;
    const int row0 = (lane >> 4) * 4;
#pragma unroll
    for (int mi = 0; mi < 4; ++mi) {
#pragma unroll
        for (int r = 0; r < 4; ++r) {
            const int gm = bm * 128 + wm + mi * 16 + row0 + r;
            const float sxr = sx[gm];
            float* orow = out + (size_t)gm * N + bn * 256 + wn;
#pragma unroll
            for (int ni = 0; ni < 8; ++ni) {
                const int gn_local = ni * 16 + col0;
                const int gn = bn * 256 + wn + gn_local;
                orow[gn_local] = (float)acc[mi][ni][r] * (sxr * sw[gn]) + bias[gn];
            }
        }
    }
    (void)M;
}

extern "C" void kernel_launch(void* const* d_in, const int* in_sizes, int n_in,
                              void* d_out, int out_size, void* d_ws, size_t ws_size,
                              hipStream_t stream) {
    const float* x    = (const float*)d_in[0];
    const float* W    = (const float*)d_in[1];
    const float* bias = (const float*)d_in[2];
    float* out = (float*)d_out;

    const int dout = in_sizes[2];               // 4096
    const int din  = in_sizes[1] / dout;        // 4096
    const int T    = in_sizes[0] / din;         // 8192

    signed char* qx = (signed char*)d_ws;
    signed char* qw = qx + (size_t)T * din;
    float* sx = (float*)(qw + (size_t)dout * din);
    float* sw = sx + T;

    quant_rows_fused<<<T + dout, 256, 0, stream>>>(x, W, qx, qw, sx, sw, T, din);

    dim3 grid(dout / 256, T / 128);
    gemm_i8_kernel<<<grid, 256, 0, stream>>>(qx, qw, sx, sw, bias, out, T, dout, din);

    (void)n_in; (void)out_size; (void)ws_size;
}

// Round 4
// 388.706 us; speedup vs baseline: 1.6993x; 1.0375x over previous
//
#include <hip/hip_runtime.h>

typedef __attribute__((ext_vector_type(4))) int int4v;
typedef __attribute__((ext_vector_type(4))) float float4v;

#define QMAX 127.0f

// ---------------- Per-row absmax int8 quantization (fused x + W) ----------------
// One block per row, 256 threads. K must be 4096 (16 elems/thread).
__global__ __launch_bounds__(256) void quant_rows_fused(
    const float* __restrict__ x, const float* __restrict__ w,
    signed char* __restrict__ qxp, signed char* __restrict__ qwp,
    float* __restrict__ sxp, float* __restrict__ swp,
    int T, int K)
{
    const int blk = blockIdx.x;
    const float* a;
    signed char* q;
    float* scale;
    int row;
    if (blk < T) { a = x; q = qxp; scale = sxp; row = blk; }
    else         { a = w; q = qwp; scale = swp; row = blk - T; }

    const int t = threadIdx.x;
    const float4v* ap = (const float4v*)(a + (size_t)row * K);

    float4v v[4];
#pragma unroll
    for (int i = 0; i < 4; ++i) v[i] = ap[t + 256 * i];

    float m = 0.f;
#pragma unroll
    for (int i = 0; i < 4; ++i) {
        m = fmaxf(m, fabsf(v[i].x));
        m = fmaxf(m, fabsf(v[i].y));
        m = fmaxf(m, fabsf(v[i].z));
        m = fmaxf(m, fabsf(v[i].w));
    }
#pragma unroll
    for (int off = 32; off > 0; off >>= 1)
        m = fmaxf(m, __shfl_down(m, off, 64));
    __shared__ float wmax[4];
    if ((t & 63) == 0) wmax[t >> 6] = m;
    __syncthreads();
    const float am = fmaxf(fmaxf(wmax[0], wmax[1]), fmaxf(wmax[2], wmax[3]));
    const float s = fmaxf(am, 1e-8f) / QMAX;
    if (t == 0) scale[row] = s;

    const double inv = 1.0 / (double)s;   // one f64 division per thread

    int* qrow = (int*)(q + (size_t)row * K);
#pragma unroll
    for (int i = 0; i < 4; ++i) {
        float r0f = (float)((double)v[i].x * inv);
        float r1f = (float)((double)v[i].y * inv);
        float r2f = (float)((double)v[i].z * inv);
        float r3f = (float)((double)v[i].w * inv);
        int b0 = (int)fminf(fmaxf(rintf(r0f), -QMAX), QMAX);
        int b1 = (int)fminf(fmaxf(rintf(r1f), -QMAX), QMAX);
        int b2 = (int)fminf(fmaxf(rintf(r2f), -QMAX), QMAX);
        int b3 = (int)fminf(fmaxf(rintf(r3f), -QMAX), QMAX);
        qrow[t + 256 * i] =
            (b0 & 0xff) | ((b1 & 0xff) << 8) | ((b2 & 0xff) << 16) | ((b3 & 0xff) << 24);
    }
}

// ---------------- int8 GEMM: 256x256 block, 8 waves, phase-interleaved ----------------
// C[t,o] = sum_k qx[t,k]*qw[o,k]. BK=64 bytes/tile, 512 threads = 8 waves
// (2M x 4N), per-wave output 128x64 = acc[8][4] of mfma_i32_16x16x64_i8.
//
// LDS: 4 buffers x (A 16 KB + B 16 KB) = 128 KB. Prefetch depth 2: while
// computing tile t (buf t&3), issue tile t+2's 4 global_load_lds into buf
// (t+2)&3 (2 per phase).
//
// RACE-FIX (round 3): tile-end is WAIT-THEN-BARRIER. vmcnt is per-wave and
// each wave stages a different LDS slice, so each wave must confirm its OWN
// loads (s_waitcnt vmcnt(4)) BEFORE the barrier; only then does the barrier
// imply "all slices landed" for everyone. Round-2 had barrier-then-wait,
// which lets a wave ds_read slices another wave hasn't finished staging.
//
// LDS xor-swizzle (proven, 0 bank conflicts): chunk (row r, 16B-col c)
// stored at col (c + (r>>1)) & 3, realized by permuting the global source
// address. Readers use cr = (kq + ((l16>>1)&3)) & 3.
//
// __launch_bounds__(512, 2): 8 waves = 2/SIMD = 1 block/CU, VGPR cap 256.
__global__ __launch_bounds__(512, 2) void gemm_i8_kernel(
    const signed char* __restrict__ qx,   // [M,K]
    const signed char* __restrict__ qw,   // [N,K]
    const float* __restrict__ sx,         // [M]
    const float* __restrict__ sw,         // [N]
    const float* __restrict__ bias,       // [N]
    float* __restrict__ out,              // [M,N]
    int M, int N, int K)
{
    __shared__ signed char sm[4 * 32768];   // buf b: A at b*32768, B at +16384

    const int t = threadIdx.x;
    const int lane = t & 63;
    const int wave = t >> 6;

    // XCD-aware bijective swizzle (nwg = 16*32 = 512, divisible by 8).
    const int nx = gridDim.x;
    const int nwg = nx * gridDim.y;
    const int bid = blockIdx.y * nx + blockIdx.x;
    const int cpx = nwg >> 3;
    const int swz = (bid & 7) * cpx + (bid >> 3);
    const int bm = swz / nx;
    const int bn = swz % nx;

    const int wm = (wave >> 2) * 128;  // wave row offset in 256 (2 M-waves)
    const int wn = (wave & 3) * 64;    // wave col offset in 256 (4 N-waves)

    int4v acc[8][4];
#pragma unroll
    for (int i = 0; i < 8; ++i)
#pragma unroll
        for (int j = 0; j < 4; ++j)
            acc[i][j] = (int4v)0;

    // Staging map: half-tile h (128 rows, 8 KB) staged by all 512 threads,
    // thread t -> chunk t: row h*128 + (t>>2), swizzled col pos t&3.
    const int r0 = t >> 2;
    const int c_src = ((t & 3) - ((t >> 3) & 3) + 4) & 3;
    const signed char* gA0 = qx + (size_t)(bm * 256 + r0) * K + c_src * 16;
    const signed char* gA1 = gA0 + (size_t)128 * K;
    const signed char* gB0 = qw + (size_t)(bn * 256 + r0) * K + c_src * 16;
    const signed char* gB1 = gB0 + (size_t)128 * K;

#define STAGE_A(Sb) do {                                                                   \
        __builtin_amdgcn_global_load_lds((const void*)gA0,                                 \
            (void*)(sm + (Sb) * 32768 + wave * 1024), 16, 0, 0);                           \
        __builtin_amdgcn_global_load_lds((const void*)gA1,                                 \
            (void*)(sm + (Sb) * 32768 + 8192 + wave * 1024), 16, 0, 0);                    \
        gA0 += 64; gA1 += 64;                                                              \
    } while (0)
#define STAGE_B(Sb) do {                                                                   \
        __builtin_amdgcn_global_load_lds((const void*)gB0,                                 \
            (void*)(sm + (Sb) * 32768 + 16384 + wave * 1024), 16, 0, 0);                   \
        __builtin_amdgcn_global_load_lds((const void*)gB1,                                 \
            (void*)(sm + (Sb) * 32768 + 16384 + 8192 + wave * 1024), 16, 0, 0);            \
        gB0 += 64; gB1 += 64;                                                              \
    } while (0)

    // Fragment read offsets. Row = (wm|wn) + (mi|ni)*16 + l16, k-quad kq.
    const int l16 = lane & 15;
    const int kq = lane >> 4;
    const int cr = (kq + ((l16 >> 1) & 3)) & 3;
    const int offA = (wm + l16) * 64 + cr * 16;
    const int offB = (wn + l16) * 64 + cr * 16;

    int4v aF[4], bF[4];
#define LOAD_A(Bb, mb) do {                                                                \
        _Pragma("unroll")                                                                  \
        for (int mi2 = 0; mi2 < 4; ++mi2)                                                  \
            aF[mi2] = *(const int4v*)(sm + (Bb) * 32768 + offA + ((mb) + mi2) * 1024);     \
    } while (0)
#define LOAD_B(Bb) do {                                                                    \
        _Pragma("unroll")                                                                  \
        for (int ni2 = 0; ni2 < 4; ++ni2)                                                  \
            bF[ni2] = *(const int4v*)(sm + (Bb) * 32768 + 16384 + offB + ni2 * 1024);      \
    } while (0)
#define MFMA16(mb) do {                                                                    \
        _Pragma("unroll")                                                                  \
        for (int mi2 = 0; mi2 < 4; ++mi2)                                                  \
            _Pragma("unroll")                                                              \
            for (int ni2 = 0; ni2 < 4; ++ni2)                                              \
                acc[(mb) + mi2][ni2] = __builtin_amdgcn_mfma_i32_16x16x64_i8(              \
                    aF[mi2], bF[ni2], acc[(mb) + mi2][ni2], 0, 0, 0);                      \
    } while (0)

#define FENCE() asm volatile("" ::: "memory")
#define WAIT_LGKM0() do { asm volatile("s_waitcnt lgkmcnt(0)" ::: "memory");               \
                          __builtin_amdgcn_sched_barrier(0); } while (0)
#define VM4() asm volatile("s_waitcnt vmcnt(4)" ::: "memory")
#define VM0() asm volatile("s_waitcnt vmcnt(0)" ::: "memory")

    // One K-tile: compute from buf Bb; stage tile t+2 into buf Sb (if DOST).
    // ENDW (the counted vmcnt wait for tile t+1's loads) executes BEFORE the
    // tile-final barrier -- wait-then-barrier (see header comment).
#define TILE(Bb, Sb, DOST, ENDW) do {                                                      \
        /* phase 0: frags a0-3 x b0-3 */                                                   \
        LOAD_A(Bb, 0); LOAD_B(Bb);                                                         \
        if (DOST) { STAGE_A(Sb); }                                                         \
        FENCE();                                                                           \
        __builtin_amdgcn_s_barrier();                                                      \
        FENCE();                                                                           \
        WAIT_LGKM0();                                                                      \
        __builtin_amdgcn_s_setprio(1);                                                     \
        MFMA16(0);                                                                         \
        __builtin_amdgcn_s_setprio(0);                                                     \
        FENCE();                                                                           \
        __builtin_amdgcn_s_barrier();                                                      \
        FENCE();                                                                           \
        /* phase 1: frags a4-7 x b0-3 (bF held in regs) */                                 \
        LOAD_A(Bb, 4);                                                                     \
        if (DOST) { STAGE_B(Sb); }                                                         \
        FENCE();                                                                           \
        __builtin_amdgcn_s_barrier();                                                      \
        FENCE();                                                                           \
        WAIT_LGKM0();                                                                      \
        __builtin_amdgcn_s_setprio(1);                                                     \
        MFMA16(4);                                                                         \
        __builtin_amdgcn_s_setprio(0);                                                     \
        FENCE();                                                                           \
        ENDW;                                   /* own next-tile loads confirmed */        \
        __builtin_amdgcn_s_barrier();           /* -> all waves' slices landed  */         \
        FENCE();                                                                           \
    } while (0)

    // Prologue: stage tiles 0 and 1; wait own tile-0 loads, THEN barrier.
    STAGE_A(0); STAGE_B(0);
    STAGE_A(1); STAGE_B(1);
    VM4();
    __builtin_amdgcn_s_barrier();
    FENCE();

    // Tiles 0..59: always stage t+2, counted vmcnt(4) at tile end.
    for (int kk = 0; kk < 60; kk += 4) {
        TILE(0, 2, true, VM4());
        TILE(1, 3, true, VM4());
        TILE(2, 0, true, VM4());
        TILE(3, 1, true, VM4());
    }
    // Tail: tiles 60..63 (stages 62, 63 issued inside 60/61).
    TILE(0, 2, true, VM4());     // tile 60: stage 62
    TILE(1, 3, true, VM4());     // tile 61: stage 63
    TILE(2, 0, false, VM0());    // tile 62: drain tile 63's loads
    TILE(3, 1, false, );         // tile 63

#undef TILE
#undef STAGE_A
#undef STAGE_B
#undef LOAD_A
#undef LOAD_B
#undef MFMA16
#undef WAIT_LGKM0
#undef VM4
#undef VM0
#undef FENCE

    // Epilogue: C/D layout col=lane&15, row=(lane>>4)*4+reg
    const int col0 = lane & 15;
    const int row0 = (lane >> 4) * 4;
#pragma unroll
    for (int mi = 0; mi < 8; ++mi) {
#pragma unroll
        for (int r = 0; r < 4; ++r) {
            const int gm = bm * 256 + wm + mi * 16 + row0 + r;
            const float sxr = sx[gm];
            float* orow = out + (size_t)gm * N + bn * 256 + wn;
#pragma unroll
            for (int ni = 0; ni < 4; ++ni) {
                const int gn_local = ni * 16 + col0;
                const int gn = bn * 256 + wn + gn_local;
                orow[gn_local] = (float)acc[mi][ni][r] * (sxr * sw[gn]) + bias[gn];
            }
        }
    }
    (void)M;
}

extern "C" void kernel_launch(void* const* d_in, const int* in_sizes, int n_in,
                              void* d_out, int out_size, void* d_ws, size_t ws_size,
                              hipStream_t stream) {
    const float* x    = (const float*)d_in[0];
    const float* W    = (const float*)d_in[1];
    const float* bias = (const float*)d_in[2];
    float* out = (float*)d_out;

    const int dout = in_sizes[2];               // 4096
    const int din  = in_sizes[1] / dout;        // 4096
    const int T    = in_sizes[0] / din;         // 8192

    signed char* qx = (signed char*)d_ws;
    signed char* qw = qx + (size_t)T * din;
    float* sx = (float*)(qw + (size_t)dout * din);
    float* sw = sx + T;

    quant_rows_fused<<<T + dout, 256, 0, stream>>>(x, W, qx, qw, sx, sw, T, din);

    dim3 grid(dout / 256, T / 256);
    gemm_i8_kernel<<<grid, 512, 0, stream>>>(qx, qw, sx, sw, bias, out, T, dout, din);

    (void)n_in; (void)out_size; (void)ws_size;
}